// Round 2
// baseline (3069.519 us; speedup 1.0000x reference)
//
#include <hip/hip_runtime.h>
#include <math.h>

#define N_IMAGE 128
#define N_REG   36
#define DIM     1024
#define MAX_WORD 60
#define OT_ITERS 20
#define MARGIN_F 0.2f
#define ALPHA_F  0.1f
#define EPS_F    1e-12f

// ws layout (floats):
//   [0, 4608)              inv_im   (1/(||im[b,r]||+eps))
//   [4608, 12288)          inv_cap  (1/(||s[i,w]||+eps))
//   [12288, 28672)         S   scores[b*128+i]
//   [28672, 45056)         SOT scores_ot[b*128+i]

__global__ void norms_kernel(const float* __restrict__ im, const float* __restrict__ s,
                             float* __restrict__ inv_im, float* __restrict__ inv_cap) {
    const int NIM = N_IMAGE * N_REG;     // 4608
    const int NS  = N_IMAGE * MAX_WORD;  // 7680
    int row  = blockIdx.x * 4 + (threadIdx.x >> 6);
    int lane = threadIdx.x & 63;
    if (row >= NIM + NS) return;
    const float* base = (row < NIM) ? (im + (size_t)row * DIM)
                                    : (s  + (size_t)(row - NIM) * DIM);
    const float4* b4 = (const float4*)base;
    float acc = 0.0f;
    for (int k = lane; k < DIM / 4; k += 64) {
        float4 v = b4[k];
        acc += v.x * v.x + v.y * v.y + v.z * v.z + v.w * v.w;
    }
    for (int off = 32; off; off >>= 1) acc += __shfl_down(acc, off, 64);
    if (lane == 0) {
        float inv = 1.0f / (sqrtf(acc) + EPS_F);
        if (row < NIM) inv_im[row] = inv;
        else           inv_cap[row - NIM] = inv;
    }
}

// One block per (caption i, image b) pair. 256 threads.
__global__ __launch_bounds__(256)
void pair_kernel(const float* __restrict__ im, const float* __restrict__ s,
                 const int* __restrict__ s_l,
                 const float* __restrict__ inv_im, const float* __restrict__ inv_cap,
                 float* __restrict__ S, float* __restrict__ SOT) {
    const int i  = blockIdx.x;   // caption
    const int b  = blockIdx.y;   // image
    const int tid = threadIdx.x;
    const int m  = s_l[i];       // n_word, 10..60

    // LDS: staging (aliased later as raw-M tile) + OT arrays
    __shared__ float stage[36 * 33 + 60 * 33];          // 3168 floats
    __shared__ float Cc[36 * 61], As[36 * 61], Ts[36 * 61], Qs[36 * 61];
    __shared__ float invImS[36], invCapS[60];
    __shared__ float deltaS[36], sigmaS[61];
    __shared__ float red[4];

    float* imS = stage;                 // [36][33]
    float* sS  = stage + 36 * 33;       // [60][33]
    float* Ms  = stage;                 // [36][60] raw dot tile, after GEMM

    if (tid < 36) invImS[tid]  = inv_im[b * 36 + tid];
    if (tid < 60) invCapS[tid] = inv_cap[i * 60 + tid];

    // ---- GEMM: M[r][w] = dot(im[b,r,:], s[i,w,:]) ----
    const int u = tid / 20;             // 0..11 (row group) when tid<240
    const int v = tid % 20;             // 0..19 (col group)
    float acc[3][3] = {{0.f,0.f,0.f},{0.f,0.f,0.f},{0.f,0.f,0.f}};

    const float4* im4 = (const float4*)(im + (size_t)b * N_REG   * DIM);
    const float4* s4  = (const float4*)(s  + (size_t)i * MAX_WORD * DIM);

    for (int k0 = 0; k0 < DIM; k0 += 32) {
        // stage im chunk: 36 rows x 8 float4
        for (int idx = tid; idx < 36 * 8; idx += 256) {
            int r = idx >> 3, kq = idx & 7;
            float4 vv = im4[r * (DIM / 4) + (k0 >> 2) + kq];
            float* dst = &imS[r * 33 + kq * 4];
            dst[0] = vv.x; dst[1] = vv.y; dst[2] = vv.z; dst[3] = vv.w;
        }
        // stage s chunk: 60 rows x 8 float4
        for (int idx = tid; idx < 60 * 8; idx += 256) {
            int w = idx >> 3, kq = idx & 7;
            float4 vv = s4[w * (DIM / 4) + (k0 >> 2) + kq];
            float* dst = &sS[w * 33 + kq * 4];
            dst[0] = vv.x; dst[1] = vv.y; dst[2] = vv.z; dst[3] = vv.w;
        }
        __syncthreads();
        if (tid < 240) {
            const float* ar = &imS[(3 * u) * 33];
            const float* br = &sS[(3 * v) * 33];
            #pragma unroll 8
            for (int k = 0; k < 32; ++k) {
                float a0 = ar[k], a1 = ar[33 + k], a2 = ar[66 + k];
                float b0 = br[k], b1 = br[33 + k], b2 = br[66 + k];
                acc[0][0] += a0 * b0; acc[0][1] += a0 * b1; acc[0][2] += a0 * b2;
                acc[1][0] += a1 * b0; acc[1][1] += a1 * b1; acc[1][2] += a1 * b2;
                acc[2][0] += a2 * b0; acc[2][1] += a2 * b1; acc[2][2] += a2 * b2;
            }
        }
        __syncthreads();
    }

    // ---- scatter M tile, build C, A, T (masked beyond m) ----
    if (tid < 240) {
        #pragma unroll
        for (int jr = 0; jr < 3; ++jr) {
            #pragma unroll
            for (int jw = 0; jw < 3; ++jw) {
                int r = 3 * u + jr, w = 3 * v + jw;
                float mval = acc[jr][jw];
                Ms[r * 60 + w] = mval;
                bool valid = (w < m);
                float c = 1.0f - mval * invImS[r] * invCapS[w];
                Cc[r * 61 + w] = valid ? c : 0.0f;
                As[r * 61 + w] = valid ? expf(-2.0f * c) : 0.0f;   // exp(-C/beta), beta=0.5
                Ts[r * 61 + w] = valid ? 1.0f : 0.0f;
            }
        }
    }
    if (tid < 36) {  // pad column 60
        Cc[tid * 61 + 60] = 0.0f; As[tid * 61 + 60] = 0.0f; Ts[tid * 61 + 60] = 0.0f;
    }
    if (tid < 61) sigmaS[tid] = (tid < m) ? (1.0f / (float)m) : 0.0f;
    __syncthreads();

    // ---- MISA sim: mean_w ( max_r M[r][w] ), w < m ----
    if (tid < 64) {
        float val = 0.0f;
        if (tid < m) {
            float mx = -INFINITY;
            for (int r = 0; r < 36; ++r) mx = fmaxf(mx, Ms[r * 60 + tid]);
            val = mx;
        }
        for (int off = 32; off; off >>= 1) val += __shfl_down(val, off, 64);
        if (tid == 0) S[b * N_IMAGE + i] = val / (float)m;
    }

    // ---- IPOT: 20 iterations on 36 x m tile ----
    for (int it = 0; it < OT_ITERS; ++it) {
        for (int o = tid; o < 36 * 61; o += 256) Qs[o] = As[o] * Ts[o];
        __syncthreads();
        if (tid < 36) {  // delta = 1/(n * Q sigma)
            const float* qr = &Qs[tid * 61];
            float ssum = 0.0f;
            #pragma unroll 4
            for (int w = 0; w < 60; ++w) ssum += qr[w] * sigmaS[w];
            deltaS[tid] = 1.0f / (36.0f * ssum);
        }
        __syncthreads();
        if (tid < 60) {  // sigma = 1/(m * Q^T delta), masked
            float ssum = 0.0f;
            #pragma unroll 4
            for (int r = 0; r < 36; ++r) ssum += Qs[r * 61 + tid] * deltaS[r];
            sigmaS[tid] = (tid < m) ? (1.0f / ((float)m * ssum)) : 0.0f;
        }
        __syncthreads();
        for (int o = tid; o < 36 * 61; o += 256) {  // T = delta * Q * sigma^T
            int r = o / 61, w = o - r * 61;
            Ts[o] = deltaS[r] * Qs[o] * sigmaS[w];
        }
        __syncthreads();
    }

    // ---- sims_ot = -sum(C * T) ----
    float part = 0.0f;
    for (int o = tid; o < 36 * 61; o += 256) part += Cc[o] * Ts[o];
    for (int off = 32; off; off >>= 1) part += __shfl_down(part, off, 64);
    if ((tid & 63) == 0) red[tid >> 6] = part;
    __syncthreads();
    if (tid == 0) SOT[b * N_IMAGE + i] = -(red[0] + red[1] + red[2] + red[3]);
}

__global__ void loss_kernel(const float* __restrict__ S, const float* __restrict__ SOT,
                            float* __restrict__ out) {
    __shared__ float dS[128], dOT[128], acc0[128], acc1[128];
    int j = threadIdx.x;  // 128 threads
    dS[j]  = S[j * 128 + j];
    dOT[j] = SOT[j * 128 + j];
    __syncthreads();

    // row pass (cost_s, axis=1 max): b = j
    float rmax_c = 0.0f, rmax_ot = 0.0f;
    float db = dS[j], dob = dOT[j];
    for (int i2 = 0; i2 < 128; ++i2) {
        if (i2 == j) continue;
        float cs  = fmaxf(0.0f, MARGIN_F + S[j * 128 + i2] - db);
        float cso = fmaxf(0.0f, MARGIN_F + SOT[j * 128 + i2] - dob);
        rmax_c  = fmaxf(rmax_c, cs + ALPHA_F * cso);
        rmax_ot = fmaxf(rmax_ot, cso);
    }
    // col pass (cost_im, axis=0 max): i = j
    float cmax_c = 0.0f, cmax_ot = 0.0f;
    for (int b2 = 0; b2 < 128; ++b2) {
        if (b2 == j) continue;
        float ci  = fmaxf(0.0f, MARGIN_F + S[b2 * 128 + j] - db);
        float cio = fmaxf(0.0f, MARGIN_F + SOT[b2 * 128 + j] - dob);
        cmax_c  = fmaxf(cmax_c, ci + ALPHA_F * cio);
        cmax_ot = fmaxf(cmax_ot, cio);
    }
    acc0[j] = rmax_c + cmax_c;
    acc1[j] = rmax_ot + cmax_ot;
    __syncthreads();
    for (int st = 64; st; st >>= 1) {
        if (j < st) { acc0[j] += acc0[j + st]; acc1[j] += acc1[j + st]; }
        __syncthreads();
    }
    if (j == 0) { out[0] = acc0[0]; out[1] = acc1[0]; }
}

extern "C" void kernel_launch(void* const* d_in, const int* in_sizes, int n_in,
                              void* d_out, int out_size, void* d_ws, size_t ws_size,
                              hipStream_t stream) {
    const float* im  = (const float*)d_in[0];
    const float* s   = (const float*)d_in[1];
    const int*   s_l = (const int*)d_in[2];
    float* out = (float*)d_out;
    float* ws  = (float*)d_ws;

    float* inv_im  = ws;
    float* inv_cap = ws + 4608;
    float* S       = ws + 12288;
    float* SOT     = ws + 12288 + 16384;

    norms_kernel<<<dim3((4608 + 7680) / 4), dim3(256), 0, stream>>>(im, s, inv_im, inv_cap);
    pair_kernel<<<dim3(N_IMAGE, N_IMAGE), dim3(256), 0, stream>>>(im, s, s_l, inv_im, inv_cap, S, SOT);
    loss_kernel<<<dim3(1), dim3(128), 0, stream>>>(S, SOT, out);
}

// Round 3
// 801.427 us; speedup vs baseline: 3.8301x; 3.8301x over previous
//
#include <hip/hip_runtime.h>
#include <hip/hip_bf16.h>
#include <math.h>

#define N_IMAGE 128
#define N_REG   36
#define DIM     1024
#define MAX_WORD 60
#define OT_ITERS 20
#define MARGIN_F 0.2f
#define ALPHA_F  0.1f
#define EPS_F    1e-12f

typedef short bf16x8 __attribute__((ext_vector_type(8)));
typedef float f32x4  __attribute__((ext_vector_type(4)));

// ---------------- helpers ----------------

__device__ __forceinline__ unsigned int pkbf2(float a, float b) {
    union { __hip_bfloat162 h2; unsigned int u; } cv;
    cv.h2 = __float22bfloat162_rn(make_float2(a, b));
    return cv.u;
}

// DPP-based full-wave (64-lane) sum. Pure VALU + 1 readlane; no LDS pipe.
#define DPP_ADD(x, ctrl) \
    ((x) + __int_as_float(__builtin_amdgcn_update_dpp(0, __float_as_int(x), (ctrl), 0xf, 0xf, true)))

__device__ __forceinline__ float wave_sum64(float x) {
    x = DPP_ADD(x, 0x111);   // row_shr:1
    x = DPP_ADD(x, 0x112);   // row_shr:2
    x = DPP_ADD(x, 0x114);   // row_shr:4
    x = DPP_ADD(x, 0x118);   // row_shr:8  -> lane15 of each 16-row has row sum
    x = DPP_ADD(x, 0x142);   // row_bcast15
    x = DPP_ADD(x, 0x143);   // row_bcast31 -> lane 63 has the 64-lane total
    return __int_as_float(__builtin_amdgcn_readlane(__float_as_int(x), 63));
}

// ---------------- norms ----------------

__global__ void norms_kernel(const float* __restrict__ im, const float* __restrict__ s,
                             float* __restrict__ inv_im, float* __restrict__ inv_cap) {
    const int NIM = N_IMAGE * N_REG;     // 4608
    const int NS  = N_IMAGE * MAX_WORD;  // 7680
    int row  = blockIdx.x * 4 + (threadIdx.x >> 6);
    int lane = threadIdx.x & 63;
    if (row >= NIM + NS) return;
    const float* base = (row < NIM) ? (im + (size_t)row * DIM)
                                    : (s  + (size_t)(row - NIM) * DIM);
    const float4* b4 = (const float4*)base;
    float acc = 0.0f;
    for (int k = lane; k < DIM / 4; k += 64) {
        float4 v = b4[k];
        acc += v.x * v.x + v.y * v.y + v.z * v.z + v.w * v.w;
    }
    for (int off = 32; off; off >>= 1) acc += __shfl_down(acc, off, 64);
    if (lane == 0) {
        float inv = 1.0f / (sqrtf(acc) + EPS_F);
        if (row < NIM) inv_im[row] = inv;
        else           inv_cap[row - NIM] = inv;
    }
}

// ---------------- fused pair kernel ----------------
// Block = (caption i, image group of 4). Wave v owns pair (i, b0+v).
// Phase 1: bf16 MFMA GEMM, M[r][w] = dot(im[b,r,:], s[i,w,:])  (48x64 padded per pair)
// Phase 2: transpose D->column ownership (lane w holds column w), register-resident
//          MISA + 20-iteration IPOT with DPP reductions (no barriers, no LDS traffic).

__global__ __launch_bounds__(256, 4)
void pair_kernel(const float* __restrict__ im, const float* __restrict__ s,
                 const int* __restrict__ s_l,
                 const float* __restrict__ inv_im, const float* __restrict__ inv_cap,
                 float* __restrict__ S, float* __restrict__ SOT) {
    const int cap = blockIdx.x;          // caption index i
    const int b0  = blockIdx.y * 4;      // first image of this block
    const int tid = threadIdx.x;
    const int lane = tid & 63;
    const int wv   = tid >> 6;           // wave id = local image
    const int q    = lane >> 4;          // quad within wave
    const int l15  = lane & 15;

    // smem: staging (A: 192 rows x 72 bf16 @144B, B: 64 rows @ +27648) aliased by
    // 4 per-wave transpose tiles float[36][65] (9360 B each) after the GEMM.
    __shared__ __align__(16) char smem[37440];
    __shared__ float invImS[144];
    __shared__ float invCapS[60];

    if (tid < 144) invImS[tid] = inv_im[b0 * 36 + tid];
    else if (tid < 204) invCapS[tid - 144] = inv_cap[cap * 60 + (tid - 144)];

    const int m = s_l[cap];              // n_word for this caption (10..60)

    const char* sA = smem;
    const char* sB = smem + 27648;

    f32x4 acc[12];
    #pragma unroll
    for (int t = 0; t < 12; ++t) acc[t] = (f32x4){0.f, 0.f, 0.f, 0.f};

    // ---- GEMM over K=1024 in 16 chunks of 64 ----
    for (int c = 0; c < 16; ++c) {
        const int c64 = c * 64;
        // stage: 256 rows (192 A padded + 64 B padded) x 16 float4-slots = 4096 items
        for (int idx = tid; idx < 4096; idx += 256) {
            const int row = idx >> 4;
            const int q4  = idx & 15;
            const float* gsrc = nullptr;
            bool valid;
            if (row < 192) {
                const int img = row / 48;
                const int r   = row - img * 48;
                valid = (r < 36);
                gsrc = im + (((size_t)((b0 + img) * 36 + r)) << 10) + c64 + q4 * 4;
            } else {
                const int r = row - 192;
                valid = (r < 60);
                gsrc = s + (((size_t)(cap * 60 + r)) << 10) + c64 + q4 * 4;
            }
            float4 v = valid ? *(const float4*)gsrc : make_float4(0.f, 0.f, 0.f, 0.f);
            uint2 w2;
            w2.x = pkbf2(v.x, v.y);
            w2.y = pkbf2(v.z, v.w);
            *(uint2*)(smem + row * 144 + q4 * 8) = w2;
        }
        __syncthreads();
        // compute: per wave, 3 row-tiles x 4 col-tiles, K=64 as 2 MFMA halves
        #pragma unroll
        for (int h = 0; h < 2; ++h) {
            bf16x8 bfr[4];
            #pragma unroll
            for (int ct = 0; ct < 4; ++ct)
                bfr[ct] = *(const bf16x8*)(sB + (ct * 16 + l15) * 144 + h * 64 + q * 16);
            #pragma unroll
            for (int rt = 0; rt < 3; ++rt) {
                bf16x8 afr = *(const bf16x8*)(sA + (wv * 48 + rt * 16 + l15) * 144 + h * 64 + q * 16);
                #pragma unroll
                for (int ct = 0; ct < 4; ++ct)
                    acc[rt * 4 + ct] = __builtin_amdgcn_mfma_f32_16x16x32_bf16(
                        afr, bfr[ct], acc[rt * 4 + ct], 0, 0, 0);
            }
        }
        __syncthreads();
    }

    // ---- transpose D (row=q*4+p, col=l15 per tile) into per-wave [36][65] f32 tile ----
    float* tr = (float*)(smem + wv * 9360);
    #pragma unroll
    for (int rt = 0; rt < 3; ++rt) {
        #pragma unroll
        for (int ct = 0; ct < 4; ++ct) {
            #pragma unroll
            for (int p = 0; p < 4; ++p) {
                if (rt < 2) {
                    int r = rt * 16 + q * 4 + p;
                    tr[r * 65 + ct * 16 + l15] = acc[rt * 4 + ct][p];
                } else if (q == 0) {
                    tr[(32 + p) * 65 + ct * 16 + l15] = acc[rt * 4 + ct][p];
                }
            }
        }
    }
    // same-wave DS ordering: LDS ops from one wave execute in order; compiler inserts lgkmcnt.

    // ---- column-owned setup: lane w holds M[:,w] ----
    const bool  validw = (lane < m);
    const float inv_m  = 1.0f / (float)m;
    const float nrm    = invCapS[lane < 60 ? lane : 0];

    float a_[36], t_[36];
    float mx = -1e30f;
    #pragma unroll
    for (int r = 0; r < 36; ++r) {
        float mv = tr[r * 65 + lane];
        mx = fmaxf(mx, mv);
        float cv = 1.0f - mv * invImS[wv * 36 + r] * nrm;   // C = 1 - cos
        a_[r] = validw ? __expf(-2.0f * cv) : 0.0f;         // A = exp(-C/beta), beta=0.5
        t_[r] = validw ? (float)m : 0.0f;                   // store T/sigma (T0=1, sigma0=1/m)
    }

    const int b = b0 + wv;
    // MISA: mean over valid w of max_r M
    float sval = wave_sum64(validw ? mx : 0.0f);
    if (lane == 0) S[(size_t)b * N_IMAGE + cap] = sval * inv_m;

    // ---- IPOT, register-resident. Invariant: T_true = t_ * sig ----
    float sig = validw ? inv_m : 0.0f;
    for (int it = 0; it < OT_ITERS; ++it) {
        const float sig2 = sig * sig;
        float sacc = 0.0f;
        #pragma unroll
        for (int r = 0; r < 36; ++r) {
            float u  = a_[r] * t_[r];                  // A∘T / sig
            float R  = wave_sum64(u * sig2);           // row-sum: Σ_w (A∘T) σ
            float dl = __builtin_amdgcn_rcpf(36.0f * R);
            sacc = fmaf(u, dl, sacc);                  // Σ_r Q δ / sig
            t_[r] = u * dl * sig;                      // new T / sig_new
        }
        sig = validw ? __builtin_amdgcn_rcpf((float)m * sig * sacc) : 0.0f;
    }

    // ---- sims_ot = -Σ C∘T ;  C recovered as -0.5*ln(A) ----
    float pp = 0.0f;
    #pragma unroll
    for (int r = 0; r < 36; ++r) {
        float cv = -0.5f * __logf(a_[r]);
        pp = fmaf(cv, t_[r], pp);
    }
    float sotv = wave_sum64(validw ? pp * sig : 0.0f);
    if (lane == 0) SOT[(size_t)b * N_IMAGE + cap] = -sotv;
}

// ---------------- loss ----------------

__global__ void loss_kernel(const float* __restrict__ S, const float* __restrict__ SOT,
                            float* __restrict__ out) {
    __shared__ float dS[128], dOT[128], acc0[128], acc1[128];
    int j = threadIdx.x;  // 128 threads
    dS[j]  = S[j * 128 + j];
    dOT[j] = SOT[j * 128 + j];
    __syncthreads();

    float rmax_c = 0.0f, rmax_ot = 0.0f;
    float db = dS[j], dob = dOT[j];
    for (int i2 = 0; i2 < 128; ++i2) {
        if (i2 == j) continue;
        float cs  = fmaxf(0.0f, MARGIN_F + S[j * 128 + i2] - db);
        float cso = fmaxf(0.0f, MARGIN_F + SOT[j * 128 + i2] - dob);
        rmax_c  = fmaxf(rmax_c, cs + ALPHA_F * cso);
        rmax_ot = fmaxf(rmax_ot, cso);
    }
    float cmax_c = 0.0f, cmax_ot = 0.0f;
    for (int b2 = 0; b2 < 128; ++b2) {
        if (b2 == j) continue;
        float ci  = fmaxf(0.0f, MARGIN_F + S[b2 * 128 + j] - db);
        float cio = fmaxf(0.0f, MARGIN_F + SOT[b2 * 128 + j] - dob);
        cmax_c  = fmaxf(cmax_c, ci + ALPHA_F * cio);
        cmax_ot = fmaxf(cmax_ot, cio);
    }
    acc0[j] = rmax_c + cmax_c;
    acc1[j] = rmax_ot + cmax_ot;
    __syncthreads();
    for (int st = 64; st; st >>= 1) {
        if (j < st) { acc0[j] += acc0[j + st]; acc1[j] += acc1[j + st]; }
        __syncthreads();
    }
    if (j == 0) { out[0] = acc0[0]; out[1] = acc1[0]; }
}

extern "C" void kernel_launch(void* const* d_in, const int* in_sizes, int n_in,
                              void* d_out, int out_size, void* d_ws, size_t ws_size,
                              hipStream_t stream) {
    const float* im  = (const float*)d_in[0];
    const float* s   = (const float*)d_in[1];
    const int*   s_l = (const int*)d_in[2];
    float* out = (float*)d_out;
    float* ws  = (float*)d_ws;

    float* inv_im  = ws;
    float* inv_cap = ws + 4608;
    float* S       = ws + 12288;
    float* SOT     = ws + 12288 + 16384;

    norms_kernel<<<dim3((4608 + 7680) / 4), dim3(256), 0, stream>>>(im, s, inv_im, inv_cap);
    pair_kernel<<<dim3(N_IMAGE, N_IMAGE / 4), dim3(256), 0, stream>>>(im, s, s_l, inv_im, inv_cap, S, SOT);
    loss_kernel<<<dim3(1), dim3(128), 0, stream>>>(S, SOT, out);
}

// Round 4
// 717.172 us; speedup vs baseline: 4.2800x; 1.1175x over previous
//
#include <hip/hip_runtime.h>
#include <hip/hip_bf16.h>
#include <math.h>

#define N_IMAGE 128
#define N_REG   36
#define DIM     1024
#define MAX_WORD 60
#define OT_ITERS 20
#define MARGIN_F 0.2f
#define ALPHA_F  0.1f
#define EPS_F    1e-12f

typedef short bf16x8 __attribute__((ext_vector_type(8)));
typedef float f32x4  __attribute__((ext_vector_type(4)));

// ---------------- helpers ----------------

__device__ __forceinline__ unsigned int pkbf2(float a, float b) {
    union { __hip_bfloat162 h2; unsigned int u; } cv;
    cv.h2 = __float22bfloat162_rn(make_float2(a, b));
    return cv.u;
}

// Full-wave (64-lane) sum, broadcast to all lanes.
// 5 xor stages within 32-lane halves on the LDS pipe (ds_swizzle), then one
// cross-half ds_bpermute with a precomputed (lane^32)*4 address. VALU cost:
// 6 adds. LDS-pipe cost: 6 ops (co-issues with other waves' VALU).
__device__ __forceinline__ float bfly_sum64(float x, int xaddr32) {
    int xi;
    xi = __builtin_amdgcn_ds_swizzle(__float_as_int(x), 0x041F); x += __int_as_float(xi); // ^1
    xi = __builtin_amdgcn_ds_swizzle(__float_as_int(x), 0x081F); x += __int_as_float(xi); // ^2
    xi = __builtin_amdgcn_ds_swizzle(__float_as_int(x), 0x101F); x += __int_as_float(xi); // ^4
    xi = __builtin_amdgcn_ds_swizzle(__float_as_int(x), 0x201F); x += __int_as_float(xi); // ^8
    xi = __builtin_amdgcn_ds_swizzle(__float_as_int(x), 0x401F); x += __int_as_float(xi); // ^16
    xi = __builtin_amdgcn_ds_bpermute(xaddr32, __float_as_int(x)); x += __int_as_float(xi); // ^32
    return x;
}

// ---------------- norms ----------------

__global__ void norms_kernel(const float* __restrict__ im, const float* __restrict__ s,
                             float* __restrict__ inv_im, float* __restrict__ inv_cap) {
    const int NIM = N_IMAGE * N_REG;     // 4608
    const int NS  = N_IMAGE * MAX_WORD;  // 7680
    int row  = blockIdx.x * 4 + (threadIdx.x >> 6);
    int lane = threadIdx.x & 63;
    if (row >= NIM + NS) return;
    const float* base = (row < NIM) ? (im + (size_t)row * DIM)
                                    : (s  + (size_t)(row - NIM) * DIM);
    const float4* b4 = (const float4*)base;
    float acc = 0.0f;
    for (int k = lane; k < DIM / 4; k += 64) {
        float4 v = b4[k];
        acc += v.x * v.x + v.y * v.y + v.z * v.z + v.w * v.w;
    }
    for (int off = 32; off; off >>= 1) acc += __shfl_down(acc, off, 64);
    if (lane == 0) {
        float inv = 1.0f / (sqrtf(acc) + EPS_F);
        if (row < NIM) inv_im[row] = inv;
        else           inv_cap[row - NIM] = inv;
    }
}

// ---------------- fused pair kernel ----------------
// Block = (caption i, image group of 4). Wave v owns pair (i, b0+v).

__global__ __launch_bounds__(256, 4)
void pair_kernel(const float* __restrict__ im, const float* __restrict__ s,
                 const int* __restrict__ s_l,
                 const float* __restrict__ inv_im, const float* __restrict__ inv_cap,
                 float* __restrict__ S, float* __restrict__ SOT) {
    const int cap  = blockIdx.x;         // caption index i
    const int b0   = blockIdx.y * 4;     // first image of this block
    const int tid  = threadIdx.x;
    const int lane = tid & 63;
    const int wv   = tid >> 6;           // wave id = local image
    const int q    = lane >> 4;          // quad within wave
    const int l15  = lane & 15;
    const int q4   = tid & 15;           // staging column slot (16B granules)
    const int row0 = tid >> 4;           // staging row base (0..15)
    const int xaddr = ((lane ^ 32) << 2);

    // staging: 256 rows x 144B bf16 (36864B), overlaid after GEMM by 4 per-wave
    // transposed tiles float[60][40] (9600B each -> 38400B).
    __shared__ __align__(16) char smem[38400];
    __shared__ float invImS[144];
    __shared__ float invCapS[60];

    if (tid < 144) invImS[tid] = inv_im[b0 * 36 + tid];
    else if (tid < 204) invCapS[tid - 144] = inv_cap[cap * 60 + (tid - 144)];

    const int   m     = s_l[cap];        // n_word, 10..60
    const float mf    = (float)m;
    const float inv_m = 1.0f / mf;

    // zero staging once: pad rows (A r>=36, B r>=60) must be 0 for MFMA.
    {
        float4 z = make_float4(0.f, 0.f, 0.f, 0.f);
        #pragma unroll
        for (int j = 0; j < 9; ++j)
            *(float4*)(smem + (tid + j * 256) * 16) = z;
    }
    __syncthreads();

    const char* sA = smem;
    const char* sB = smem + 27648;

    f32x4 acc[12];
    #pragma unroll
    for (int t = 0; t < 12; ++t) acc[t] = (f32x4){0.f, 0.f, 0.f, 0.f};

    // global bases: this thread always reads 16B granule q4 of some row
    const float* baseA = im + ((size_t)b0 * 36) * 1024 + q4 * 4;
    const float* baseB = s  + ((size_t)cap * 60) * 1024 + q4 * 4;

    // ---- GEMM over K=1024 in 16 chunks of 64 ----
    for (int c = 0; c < 16; ++c) {
        const float* pA = baseA + c * 64;
        const float* pB = baseB + c * 64;
        // A: 4 images x 3 row-slots (rows row0, row0+16, row0+32 of 48-padded tile)
        #pragma unroll
        for (int img = 0; img < 4; ++img) {
            #pragma unroll
            for (int j = 0; j < 3; ++j) {
                const int r = row0 + 16 * j;                 // < 48
                if (j < 2 || row0 < 4) {                     // valid iff r < 36
                    float4 v = *(const float4*)(pA + ((size_t)(img * 36 + r)) * 1024);
                    uint2 w2; w2.x = pkbf2(v.x, v.y); w2.y = pkbf2(v.z, v.w);
                    *(uint2*)(smem + (img * 48 + r) * 144 + q4 * 8) = w2;
                }
            }
        }
        // B: 4 row-slots (rows row0 .. row0+48 of 64-padded tile)
        #pragma unroll
        for (int j = 0; j < 4; ++j) {
            const int r = row0 + 16 * j;                     // < 64
            if (j < 3 || row0 < 12) {                        // valid iff r < 60
                float4 v = *(const float4*)(pB + (size_t)r * 1024);
                uint2 w2; w2.x = pkbf2(v.x, v.y); w2.y = pkbf2(v.z, v.w);
                *(uint2*)(smem + (192 + r) * 144 + q4 * 8) = w2;
            }
        }
        __syncthreads();
        // per wave: 3 row-tiles x 4 col-tiles, K=64 as 2 MFMA halves
        #pragma unroll
        for (int h = 0; h < 2; ++h) {
            bf16x8 bfr[4];
            #pragma unroll
            for (int ct = 0; ct < 4; ++ct)
                bfr[ct] = *(const bf16x8*)(sB + (ct * 16 + l15) * 144 + h * 64 + q * 16);
            #pragma unroll
            for (int rt = 0; rt < 3; ++rt) {
                bf16x8 afr = *(const bf16x8*)(sA + (wv * 48 + rt * 16 + l15) * 144 + h * 64 + q * 16);
                #pragma unroll
                for (int ct = 0; ct < 4; ++ct)
                    acc[rt * 4 + ct] = __builtin_amdgcn_mfma_f32_16x16x32_bf16(
                        afr, bfr[ct], acc[rt * 4 + ct], 0, 0, 0);
            }
        }
        __syncthreads();
    }

    // ---- transpose D into per-wave column-major tile [w][40] (b128 ops) ----
    // D element (row = rt*16 + q*4 + p, col w = ct*16 + l15) = acc[rt*4+ct][p]
    float* tw = (float*)(smem + wv * 9600);
    #pragma unroll
    for (int ct = 0; ct < 4; ++ct) {
        const int w = ct * 16 + l15;
        if (ct < 3 || l15 < 12) {                    // w < 60
            #pragma unroll
            for (int rt = 0; rt < 3; ++rt) {
                if (rt < 2 || q == 0) {              // row < 36
                    float4 vv;
                    vv.x = acc[rt * 4 + ct][0]; vv.y = acc[rt * 4 + ct][1];
                    vv.z = acc[rt * 4 + ct][2]; vv.w = acc[rt * 4 + ct][3];
                    *(float4*)(tw + w * 40 + rt * 16 + q * 4) = vv;
                }
            }
        }
    }
    // same-wave LDS RAW is ordered (compiler lgkmcnt) — no barrier needed.

    // ---- column-owned OT setup: lane w holds M[:,w] ----
    const bool  validw = (lane < m);
    const float nrm    = invCapS[lane < 60 ? lane : 0];
    const int   lw     = (lane < 60) ? lane : 59;
    const float4* tr4  = (const float4*)(tw + lw * 40);

    float a_[36], t_[36];
    float mx = -1e30f;
    #pragma unroll
    for (int k = 0; k < 9; ++k) {
        float4 mv = tr4[k];
        #pragma unroll
        for (int p = 0; p < 4; ++p) {
            const int r = 4 * k + p;
            const float mvv = (p == 0) ? mv.x : (p == 1) ? mv.y : (p == 2) ? mv.z : mv.w;
            mx = fmaxf(mx, mvv);
            float cv = 1.0f - mvv * invImS[wv * 36 + r] * nrm;   // C = 1 - cos
            a_[r] = validw ? __expf(-2.0f * cv) : 0.0f;          // A = exp(-C/beta)
            t_[r] = validw ? mf : 0.0f;                          // t = T/sigma, T0=1, sig0=1/m
        }
    }

    const int b = b0 + wv;
    // MISA: mean over valid w of max_r M
    float sval = bfly_sum64(validw ? mx : 0.0f, xaddr);
    if (lane == 0) S[(size_t)b * N_IMAGE + cap] = sval * inv_m;

    // ---- IPOT. Invariant: t_ = T/sigma  (so Q = A∘T = (a*t)*sig exactly) ----
    float sig = validw ? inv_m : 0.0f;
    for (int it = 0; it < OT_ITERS; ++it) {
        float sacc = 0.0f;
        #pragma unroll
        for (int r = 0; r < 36; ++r) {
            float at = a_[r] * t_[r];
            float Q  = at * sig;                    // Q[r,w]
            float R  = bfly_sum64(Q * sig, xaddr);  // Σ_w Q σ
            float dl = __builtin_amdgcn_rcpf(36.0f * R);
            float tn = dl * Q;                      // t_new = δ Q = T_new/σ_new
            t_[r] = tn;
            sacc += tn;                             // Σ_r δ Q  (per column w)
        }
        sig = validw ? __builtin_amdgcn_rcpf(mf * sacc) : 0.0f;
    }

    // ---- sims_ot = -Σ C∘T ;  C = -0.5 ln(A) ----
    float pp = 0.0f;
    #pragma unroll
    for (int r = 0; r < 36; ++r) {
        float cv = -0.5f * __logf(a_[r]);
        pp = fmaf(cv, t_[r], pp);
    }
    float sot = bfly_sum64(validw ? pp * sig : 0.0f, xaddr);
    if (lane == 0) SOT[(size_t)b * N_IMAGE + cap] = -sot;
}

// ---------------- loss ----------------

__global__ void loss_kernel(const float* __restrict__ S, const float* __restrict__ SOT,
                            float* __restrict__ out) {
    __shared__ float dS[128], dOT[128], acc0[128], acc1[128];
    int j = threadIdx.x;  // 128 threads
    dS[j]  = S[j * 128 + j];
    dOT[j] = SOT[j * 128 + j];
    __syncthreads();

    float rmax_c = 0.0f, rmax_ot = 0.0f;
    float db = dS[j], dob = dOT[j];
    for (int i2 = 0; i2 < 128; ++i2) {
        if (i2 == j) continue;
        float cs  = fmaxf(0.0f, MARGIN_F + S[j * 128 + i2] - db);
        float cso = fmaxf(0.0f, MARGIN_F + SOT[j * 128 + i2] - dob);
        rmax_c  = fmaxf(rmax_c, cs + ALPHA_F * cso);
        rmax_ot = fmaxf(rmax_ot, cso);
    }
    float cmax_c = 0.0f, cmax_ot = 0.0f;
    for (int b2 = 0; b2 < 128; ++b2) {
        if (b2 == j) continue;
        float ci  = fmaxf(0.0f, MARGIN_F + S[b2 * 128 + j] - db);
        float cio = fmaxf(0.0f, MARGIN_F + SOT[b2 * 128 + j] - dob);
        cmax_c  = fmaxf(cmax_c, ci + ALPHA_F * cio);
        cmax_ot = fmaxf(cmax_ot, cio);
    }
    acc0[j] = rmax_c + cmax_c;
    acc1[j] = rmax_ot + cmax_ot;
    __syncthreads();
    for (int st = 64; st; st >>= 1) {
        if (j < st) { acc0[j] += acc0[j + st]; acc1[j] += acc1[j + st]; }
        __syncthreads();
    }
    if (j == 0) { out[0] = acc0[0]; out[1] = acc1[0]; }
}

extern "C" void kernel_launch(void* const* d_in, const int* in_sizes, int n_in,
                              void* d_out, int out_size, void* d_ws, size_t ws_size,
                              hipStream_t stream) {
    const float* im  = (const float*)d_in[0];
    const float* s   = (const float*)d_in[1];
    const int*   s_l = (const int*)d_in[2];
    float* out = (float*)d_out;
    float* ws  = (float*)d_ws;

    float* inv_im  = ws;
    float* inv_cap = ws + 4608;
    float* S       = ws + 12288;
    float* SOT     = ws + 12288 + 16384;

    norms_kernel<<<dim3((4608 + 7680) / 4), dim3(256), 0, stream>>>(im, s, inv_im, inv_cap);
    pair_kernel<<<dim3(N_IMAGE, N_IMAGE / 4), dim3(256), 0, stream>>>(im, s, s_l, inv_im, inv_cap, S, SOT);
    loss_kernel<<<dim3(1), dim3(128), 0, stream>>>(S, SOT, out);
}

// Round 5
// 501.994 us; speedup vs baseline: 6.1147x; 1.4286x over previous
//
#include <hip/hip_runtime.h>
#include <hip/hip_bf16.h>
#include <math.h>

#define N_IMAGE 128
#define N_REG   36
#define DIM     1024
#define MAX_WORD 60
#define OT_ITERS 20
#define MARGIN_F 0.2f
#define ALPHA_F  0.1f
#define EPS_F    1e-12f

typedef short bf16x8 __attribute__((ext_vector_type(8)));
typedef float f32x4  __attribute__((ext_vector_type(4)));

// ---------------- helpers ----------------

__device__ __forceinline__ unsigned int pkbf2(float a, float b) {
    union { __hip_bfloat162 h2; unsigned int u; } cv;
    cv.h2 = __float22bfloat162_rn(make_float2(a, b));
    return cv.u;
}
__device__ __forceinline__ float lo16(unsigned int u) { return __int_as_float((int)(u << 16)); }
__device__ __forceinline__ float hi16(unsigned int u) { return __int_as_float((int)(u & 0xFFFF0000u)); }

#define SWZ(x, pat) __int_as_float(__builtin_amdgcn_ds_swizzle(__float_as_int(x), (pat)))
#define BPERM(a, x) __int_as_float(__builtin_amdgcn_ds_bpermute((a), __float_as_int(x)))

// xor-butterfly sum over the 16-lane group (all lanes get the group sum)
__device__ __forceinline__ float bfly16_sum(float x) {
    x += SWZ(x, 0x041F);   // ^1
    x += SWZ(x, 0x081F);   // ^2
    x += SWZ(x, 0x101F);   // ^4
    x += SWZ(x, 0x201F);   // ^8
    return x;
}
// full 64-lane xor-butterfly sum (all lanes)
__device__ __forceinline__ float bfly64_sum(float x, int xaddr) {
    x = bfly16_sum(x);
    x += SWZ(x, 0x401F);   // ^16
    x += BPERM(xaddr, x);  // ^32
    return x;
}

// ---------------- norms (+ zero d_out for loss atomics) ----------------

__global__ void norms_kernel(const float* __restrict__ im, const float* __restrict__ s,
                             float* __restrict__ inv_im, float* __restrict__ inv_cap,
                             float* __restrict__ out) {
    if (blockIdx.x == 0 && threadIdx.x == 0) { out[0] = 0.0f; out[1] = 0.0f; }
    const int NIM = N_IMAGE * N_REG;     // 4608
    const int NS  = N_IMAGE * MAX_WORD;  // 7680
    int row  = blockIdx.x * 4 + (threadIdx.x >> 6);
    int lane = threadIdx.x & 63;
    if (row >= NIM + NS) return;
    const float* base = (row < NIM) ? (im + (size_t)row * DIM)
                                    : (s  + (size_t)(row - NIM) * DIM);
    const float4* b4 = (const float4*)base;
    float acc = 0.0f;
    for (int k = lane; k < DIM / 4; k += 64) {
        float4 v = b4[k];
        acc += v.x * v.x + v.y * v.y + v.z * v.z + v.w * v.w;
    }
    for (int off = 32; off; off >>= 1) acc += __shfl_down(acc, off, 64);
    if (lane == 0) {
        float inv = 1.0f / (sqrtf(acc) + EPS_F);
        if (row < NIM) inv_im[row] = inv;
        else           inv_cap[row - NIM] = inv;
    }
}

// ---------------- fused pair kernel ----------------
// Block = (caption i, image group of 4). Wave v owns pair (i, b0+v).
// GEMM: bf16 MFMA, D stays in MFMA C-layout: acc[rt*4+ct][p] = M[r][w],
//   r = rt*16 + q*4 + p   (q = lane>>4; rows 36..47 are zero padding)
//   w = ct*16 + l15       (l15 = lane&15; cols 60..63 padding)
// OT runs directly in this layout: each 16-lane group (fixed q) holds complete
// rows -> row-sums are 4-stage 16-lane butterflies; sigma-update is ^16+^32.

__global__ __launch_bounds__(256, 4)
void pair_kernel(const float* __restrict__ im, const float* __restrict__ s,
                 const int* __restrict__ s_l,
                 const float* __restrict__ inv_im, const float* __restrict__ inv_cap,
                 float* __restrict__ S, float* __restrict__ SOT) {
    const int cap  = blockIdx.x;         // caption index i
    const int b0   = blockIdx.y * 4;     // first image of this block
    const int tid  = threadIdx.x;
    const int lane = tid & 63;
    const int wv   = tid >> 6;           // wave id = local image
    const int q    = lane >> 4;          // 16-lane group within wave
    const int l15  = lane & 15;
    const int q4   = tid & 15;           // staging column slot (16B granules)
    const int row0 = tid >> 4;           // staging row base (0..15)
    const int xaddr = ((lane ^ 32) << 2);

    // staging: 256 rows x 144B bf16 (36864B). No transpose tile needed.
    __shared__ __align__(16) char smem[36864];
    __shared__ float invImS[144];
    __shared__ float invCapS[60];

    if (tid < 144) invImS[tid] = inv_im[b0 * 36 + tid];
    else if (tid < 204) invCapS[tid - 144] = inv_cap[cap * 60 + (tid - 144)];

    const int   m     = s_l[cap];        // n_word, 10..60
    const float mf    = (float)m;
    const float inv_m = 1.0f / mf;

    // zero staging once: pad rows (A r>=36, B r>=60) must be 0 for MFMA.
    {
        float4 z = make_float4(0.f, 0.f, 0.f, 0.f);
        #pragma unroll
        for (int j = 0; j < 9; ++j)
            *(float4*)(smem + (tid + j * 256) * 16) = z;
    }
    __syncthreads();

    const char* sA = smem;
    const char* sB = smem + 27648;

    f32x4 acc[12];
    #pragma unroll
    for (int t = 0; t < 12; ++t) acc[t] = (f32x4){0.f, 0.f, 0.f, 0.f};

    const float* baseA = im + ((size_t)b0 * 36) * 1024 + q4 * 4;
    const float* baseB = s  + ((size_t)cap * 60) * 1024 + q4 * 4;

    // ---- GEMM over K=1024 in 16 chunks of 64 ----
    for (int c = 0; c < 16; ++c) {
        const float* pA = baseA + c * 64;
        const float* pB = baseB + c * 64;
        #pragma unroll
        for (int img = 0; img < 4; ++img) {
            #pragma unroll
            for (int j = 0; j < 3; ++j) {
                const int r = row0 + 16 * j;                 // < 48
                if (j < 2 || row0 < 4) {                     // valid iff r < 36
                    float4 v = *(const float4*)(pA + ((size_t)(img * 36 + r)) * 1024);
                    uint2 w2; w2.x = pkbf2(v.x, v.y); w2.y = pkbf2(v.z, v.w);
                    *(uint2*)(smem + (img * 48 + r) * 144 + q4 * 8) = w2;
                }
            }
        }
        #pragma unroll
        for (int j = 0; j < 4; ++j) {
            const int r = row0 + 16 * j;                     // < 64
            if (j < 3 || row0 < 12) {                        // valid iff r < 60
                float4 v = *(const float4*)(pB + (size_t)r * 1024);
                uint2 w2; w2.x = pkbf2(v.x, v.y); w2.y = pkbf2(v.z, v.w);
                *(uint2*)(smem + (192 + r) * 144 + q4 * 8) = w2;
            }
        }
        __syncthreads();
        #pragma unroll
        for (int h = 0; h < 2; ++h) {
            bf16x8 bfr[4];
            #pragma unroll
            for (int ct = 0; ct < 4; ++ct)
                bfr[ct] = *(const bf16x8*)(sB + (ct * 16 + l15) * 144 + h * 64 + q * 16);
            #pragma unroll
            for (int rt = 0; rt < 3; ++rt) {
                bf16x8 afr = *(const bf16x8*)(sA + (wv * 48 + rt * 16 + l15) * 144 + h * 64 + q * 16);
                #pragma unroll
                for (int ct = 0; ct < 4; ++ct)
                    acc[rt * 4 + ct] = __builtin_amdgcn_mfma_f32_16x16x32_bf16(
                        afr, bfr[ct], acc[rt * 4 + ct], 0, 0, 0);
            }
        }
        __syncthreads();
    }

    // ---- OT setup in C-layout ----
    // per-lane column info (4 columns: w = ct*16 + l15)
    float icap[4]; bool vw[4];
    #pragma unroll
    for (int ct = 0; ct < 4; ++ct) {
        const int w = ct * 16 + l15;
        vw[ct]   = (w < m);
        icap[ct] = (w < 60) ? invCapS[w] : 0.0f;
    }

    float        t_[12][4];      // t = T/sigma
    unsigned int apk[12][2];     // A = exp(-2C), packed bf16 pairs (ct0,ct1),(ct2,ct3)
    float mxv[4] = {-3e38f, -3e38f, -3e38f, -3e38f};

    #pragma unroll
    for (int j = 0; j < 12; ++j) {
        const int rt = j >> 2, p = j & 3;
        const int r  = rt * 16 + q * 4 + p;                  // < 48
        const bool rowok = (rt < 2) || (q == 0);             // r < 36
        const float iir = rowok ? invImS[wv * 36 + (r < 36 ? r : 0)] : 0.0f;
        float av[4];
        #pragma unroll
        for (int ct = 0; ct < 4; ++ct) {
            const float Mv = acc[rt * 4 + ct][p];
            mxv[ct] = fmaxf(mxv[ct], rowok ? Mv : -3e38f);
            const float cv = 1.0f - Mv * iir * icap[ct];     // C = 1 - cos
            const bool ok  = rowok && vw[ct];
            av[ct]   = ok ? __expf(-2.0f * cv) : 0.0f;       // A = exp(-C/beta)
            t_[j][ct] = ok ? mf : 0.0f;                      // t0 = T0/sig0 = m
        }
        apk[j][0] = pkbf2(av[0], av[1]);
        apk[j][1] = pkbf2(av[2], av[3]);
    }

    const int b = b0 + wv;
    // ---- MISA: mean_w max_r M ----
    {
        float sp = 0.0f;
        #pragma unroll
        for (int ct = 0; ct < 4; ++ct) {
            float v = mxv[ct];
            v = fmaxf(v, SWZ(v, 0x401F));
            v = fmaxf(v, BPERM(xaddr, v));
            sp += vw[ct] ? v : 0.0f;
        }
        sp = bfly64_sum(sp, xaddr);      // = 4 * sum_w colmax (q-replicated)
        if (lane == 0) S[(size_t)b * N_IMAGE + cap] = sp * inv_m * 0.25f;
    }

    // ---- IPOT: 20 iterations, register-resident, 16-lane butterflies ----
    float sig[4];
    #pragma unroll
    for (int ct = 0; ct < 4; ++ct) sig[ct] = vw[ct] ? inv_m : 0.0f;

    for (int it = 0; it < OT_ITERS; ++it) {
        float s2[4];
        #pragma unroll
        for (int ct = 0; ct < 4; ++ct) s2[ct] = sig[ct] * sig[ct];
        float csum[4] = {0.f, 0.f, 0.f, 0.f};
        #pragma unroll
        for (int j = 0; j < 12; ++j) {
            float at[4];
            at[0] = lo16(apk[j][0]) * t_[j][0];
            at[1] = hi16(apk[j][0]) * t_[j][1];
            at[2] = lo16(apk[j][1]) * t_[j][2];
            at[3] = hi16(apk[j][1]) * t_[j][3];
            float u = at[0] * s2[0];
            u = fmaf(at[1], s2[1], u);
            u = fmaf(at[2], s2[2], u);
            u = fmaf(at[3], s2[3], u);
            float R  = bfly16_sum(u);                        // row-sum: Σ_w Qσ
            float dl = __builtin_amdgcn_rcpf(36.0f * R);     // delta for this lane's row
            if (j >= 8) dl = (q == 0) ? dl : 0.0f;           // pad-row guard (R=0 -> inf)
            #pragma unroll
            for (int ct = 0; ct < 4; ++ct) {
                const float tn = at[ct] * (dl * sig[ct]);    // t_new = δQ
                t_[j][ct] = tn;
                csum[ct] += tn;                              // Σ_r δQ (partial, this q)
            }
        }
        #pragma unroll
        for (int ct = 0; ct < 4; ++ct) {
            float c = csum[ct];
            c += SWZ(c, 0x401F);                             // ^16 (across q)
            c += BPERM(xaddr, c);                            // ^32
            sig[ct] = vw[ct] ? __builtin_amdgcn_rcpf(mf * c) : 0.0f;
        }
    }

    // ---- sims_ot = -Σ C∘T ;  C = -0.5 ln(A), T = t*sig ----
    {
        float pp = 0.0f;
        #pragma unroll
        for (int j = 0; j < 12; ++j) {
            float av[4];
            av[0] = lo16(apk[j][0]); av[1] = hi16(apk[j][0]);
            av[2] = lo16(apk[j][1]); av[3] = hi16(apk[j][1]);
            #pragma unroll
            for (int ct = 0; ct < 4; ++ct) {
                const float cv = -0.5f * __logf(fmaxf(av[ct], 1e-30f));
                pp = fmaf(cv, t_[j][ct] * sig[ct], pp);
            }
        }
        pp = bfly64_sum(pp, xaddr);      // every cell counted once
        if (lane == 0) SOT[(size_t)b * N_IMAGE + cap] = -pp;
    }
}

// ---------------- loss: 128 blocks, one per row/col pair, atomic accumulate ----

__global__ void loss_kernel(const float* __restrict__ S, const float* __restrict__ SOT,
                            float* __restrict__ out) {
    const int j = blockIdx.x;
    const int t = threadIdx.x;           // 128 threads
    __shared__ float sh[4][2];
    const float db  = S[j * 129];        // diag
    const float dob = SOT[j * 129];
    float rv = 0.f, rov = 0.f, cv = 0.f, cov = 0.f;
    if (t != j) {
        float cs  = fmaxf(0.0f, MARGIN_F + S[j * 128 + t] - db);
        float cso = fmaxf(0.0f, MARGIN_F + SOT[j * 128 + t] - dob);
        rv = cs + ALPHA_F * cso;  rov = cso;
        float ci  = fmaxf(0.0f, MARGIN_F + S[t * 128 + j] - db);
        float cio = fmaxf(0.0f, MARGIN_F + SOT[t * 128 + j] - dob);
        cv = ci + ALPHA_F * cio;  cov = cio;
    }
    for (int off = 32; off; off >>= 1) {
        rv  = fmaxf(rv,  __shfl_down(rv,  off, 64));
        rov = fmaxf(rov, __shfl_down(rov, off, 64));
        cv  = fmaxf(cv,  __shfl_down(cv,  off, 64));
        cov = fmaxf(cov, __shfl_down(cov, off, 64));
    }
    if ((t & 63) == 0) {
        sh[0][t >> 6] = rv; sh[1][t >> 6] = rov;
        sh[2][t >> 6] = cv; sh[3][t >> 6] = cov;
    }
    __syncthreads();
    if (t == 0) {
        float a0 = fmaxf(sh[0][0], sh[0][1]) + fmaxf(sh[2][0], sh[2][1]);
        float a1 = fmaxf(sh[1][0], sh[1][1]) + fmaxf(sh[3][0], sh[3][1]);
        atomicAdd(&out[0], a0);
        atomicAdd(&out[1], a1);
    }
}

extern "C" void kernel_launch(void* const* d_in, const int* in_sizes, int n_in,
                              void* d_out, int out_size, void* d_ws, size_t ws_size,
                              hipStream_t stream) {
    const float* im  = (const float*)d_in[0];
    const float* s   = (const float*)d_in[1];
    const int*   s_l = (const int*)d_in[2];
    float* out = (float*)d_out;
    float* ws  = (float*)d_ws;

    float* inv_im  = ws;
    float* inv_cap = ws + 4608;
    float* S       = ws + 12288;
    float* SOT     = ws + 12288 + 16384;

    norms_kernel<<<dim3((4608 + 7680) / 4), dim3(256), 0, stream>>>(im, s, inv_im, inv_cap, out);
    pair_kernel<<<dim3(N_IMAGE, N_IMAGE / 4), dim3(256), 0, stream>>>(im, s, s_l, inv_im, inv_cap, S, SOT);
    loss_kernel<<<dim3(N_IMAGE), dim3(128), 0, stream>>>(S, SOT, out);
}